// Round 4
// baseline (683.071 us; speedup 1.0000x reference)
//
#include <hip/hip_runtime.h>
#include <math.h>

#define BN_SCALE 0.9999950000374997f

typedef unsigned short u16;
typedef short bfrag8 __attribute__((ext_vector_type(8)));
typedef float floatx4 __attribute__((ext_vector_type(4)));

struct ushort4_t { u16 x, y, z, w; };

__device__ __forceinline__ u16 f2bf(float f) {
  union { float f; unsigned u; } c; c.f = f;
  unsigned r = c.u + 0x7FFFu + ((c.u >> 16) & 1u);
  return (u16)(r >> 16);
}

__device__ __forceinline__ void gload_lds16(const u16* g, u16* l) {
  __builtin_amdgcn_global_load_lds(
      (const __attribute__((address_space(1))) void*)g,
      (__attribute__((address_space(3))) void*)l, 16, 0, 0);
}

__device__ __forceinline__ floatx4 mfma16(bfrag8 a, bfrag8 b, floatx4 c) {
  return __builtin_amdgcn_mfma_f32_16x16x32_bf16(a, b, c, 0, 0, 0);
}

// qB/kB fragment layout (u16):
//   offset(n,tile,kc,rb,lane,e) = (((n*48+tile)*16 + kc)*12 + rb)*512 + lane*8 + e
// where kc = kk*2+k2 (k-slice of 32), rb = row-block (16 rows), lane = lq*16+lr
// holds element [row = rb*16+lr][k = kc*32 + lq*8 + e].  One 16B dwordx4 per lane.

// ---------------- K0: prep — gate sigmoid, w2*alpha -> bf16, beta2 ----------------
__global__ void k_prep(const float* __restrict__ se, float* __restrict__ gate,
                       const float* __restrict__ w2, const float* __restrict__ g2,
                       const float* __restrict__ b2, const float* __restrict__ bb2,
                       u16* __restrict__ w2B, float* __restrict__ beta2) {
  int idx = blockIdx.x * 256 + threadIdx.x;
  if (idx < 110592) {
    float x = se[idx];
    gate[idx] = 1.0f / (1.0f + expf(-x));
    return;
  }
  idx -= 110592;
  if (idx < 1179648) {
    int nf = idx / 192;  // n*2048 + f
    w2B[idx] = f2bf(w2[idx] * (g2[nf] * BN_SCALE));
    return;
  }
  idx -= 1179648;
  if (idx < 6144) beta2[idx] = b2[idx] * (g2[idx] * BN_SCALE) + bb2[idx];
}

// ---------------- K2: fc1 GEMM -> fragment-layout qB/kB ----------------
// A rows: memory/features reshaped [9216][n*512+d], ld=1536 (f32). Tile 128x128, BK=64.
__global__ __launch_bounds__(256, 1) void k_fc1(
    const float* __restrict__ memin, const float* __restrict__ featin,
    const float* __restrict__ w1, const float* __restrict__ b1,
    u16* __restrict__ qB, u16* __restrict__ kB) {
  __shared__ u16 At[128 * 64];
  __shared__ u16 Bt[128 * 64];
  const int tid = threadIdx.x, lane = tid & 63, wave = tid >> 6;
  const int bz = blockIdx.z, n = bz >> 1, side = bz & 1;
  const int m0 = blockIdx.y * 128, n0 = blockIdx.x * 128;
  const float* A = (side ? featin : memin) + n * 512;   // ld 1536
  const float* B = w1 + (size_t)n * 512 * 512;          // ld 512
  u16* Cn = (side ? kB : qB) + (size_t)n * 4718592;

  floatx4 acc[4][4];
  for (int i = 0; i < 4; i++)
    for (int j = 0; j < 4; j++) acc[i][j] = (floatx4){0.f, 0.f, 0.f, 0.f};
  const int wr = wave >> 1, wc = wave & 1;
  const int lr = lane & 15, lq = lane >> 4;

  for (int kk = 0; kk < 8; ++kk) {
    const int k0 = kk * 64;
    __syncthreads();
    for (int it = 0; it < 8; ++it) {
      int s = it * 256 + tid;               // float4 index within 128x64 tile
      int row = s >> 4, c4 = (s & 15) << 2;
      float4 av = *(const float4*)&A[(size_t)(m0 + row) * 1536 + k0 + c4];
      ushort4_t ah = {f2bf(av.x), f2bf(av.y), f2bf(av.z), f2bf(av.w)};
      *(ushort4_t*)&At[row * 64 + c4] = ah;
      float4 bv = *(const float4*)&B[(size_t)(n0 + row) * 512 + k0 + c4];
      ushort4_t bh = {f2bf(bv.x), f2bf(bv.y), f2bf(bv.z), f2bf(bv.w)};
      *(ushort4_t*)&Bt[row * 64 + c4] = bh;
    }
    __syncthreads();
    for (int k2 = 0; k2 < 64; k2 += 32) {
      bfrag8 a[4], b[4];
      for (int i = 0; i < 4; i++)
        a[i] = *(const bfrag8*)&At[(wr * 64 + i * 16 + lr) * 64 + k2 + lq * 8];
      for (int j = 0; j < 4; j++)
        b[j] = *(const bfrag8*)&Bt[(wc * 64 + j * 16 + lr) * 64 + k2 + lq * 8];
      for (int i = 0; i < 4; i++)
        for (int j = 0; j < 4; j++) acc[i][j] = mfma16(a[i], b[j], acc[i][j]);
    }
  }
  for (int j = 0; j < 4; j++) {
    int col = n0 + wc * 64 + j * 16 + lr;
    float bias = b1[n * 512 + col];
    int kc = col >> 5;                      // kk*2+k2
    int lq2 = (col >> 3) & 3, e = col & 7;
    for (int i = 0; i < 4; i++) {
      int rbase = m0 + wr * 64 + i * 16 + lq * 4;
      for (int rg = 0; rg < 4; rg++) {
        int rr = rbase + rg;
        int tile = rr / 192, rw = rr - tile * 192;
        int rb = rw >> 4, lrD = rw & 15;
        Cn[(((size_t)tile * 16 + kc) * 12 + rb) * 512 + (lq2 * 16 + lrD) * 8 + e] =
            f2bf(acc[i][j][rg] + bias);
      }
    }
  }
}

// ---------------- K3: per (n,q,k): gated 192x192 score + dual max-pool + bn1 --------
// Barrier-free K-loop: fragments loaded straight from global (fragment-layout qB/kB).
// 4 waves, each 96x96 (acc[6][6]).  XCD swizzle keeps 6 k-tiles per XCD L2-resident.
__global__ __launch_bounds__(256, 2) void k_score(
    const u16* __restrict__ qB, const u16* __restrict__ kB,
    const float* __restrict__ gate,
    const float* __restrict__ bn1g, const float* __restrict__ bn1b,
    u16* __restrict__ pooled) {
  __shared__ float colL[8 * 192];
  __shared__ float rowL[2 * 192];
  const int tid = threadIdx.x, lane = tid & 63, wave = tid >> 6;
  const int lin = blockIdx.x, n = blockIdx.y;
  const int xcd = lin & 7, idx = lin >> 3;
  const int qIdx = idx / 6, kIdx = xcd * 6 + (idx - (idx / 6) * 6);
  const int ws = wave >> 1, wt = wave & 1;
  const int lr = lane & 15, lq = lane >> 4;

  const u16* Ap = kB + (((size_t)(n * 48 + kIdx) * 16) * 12 + ws * 6) * 512 + lane * 8;
  const u16* Bp = qB + (((size_t)(n * 48 + qIdx) * 16) * 12 + wt * 6) * 512 + lane * 8;

  floatx4 acc[6][6];
  for (int i = 0; i < 6; i++)
    for (int j = 0; j < 6; j++) acc[i][j] = (floatx4){0.f, 0.f, 0.f, 0.f};

#pragma unroll 4
  for (int kc = 0; kc < 16; ++kc) {
    bfrag8 a[6], b[6];
#pragma unroll
    for (int i = 0; i < 6; i++) a[i] = *(const bfrag8*)(Ap + i * 512);
#pragma unroll
    for (int j = 0; j < 6; j++) b[j] = *(const bfrag8*)(Bp + j * 512);
#pragma unroll
    for (int i = 0; i < 6; i++)
#pragma unroll
      for (int j = 0; j < 6; j++) acc[i][j] = mfma16(a[i], b[j], acc[i][j]);
    Ap += 6144;
    Bp += 6144;
  }

  const float* gaten = gate + (size_t)n * 36864;
  float colp[6], rowp[6][4];
  for (int j = 0; j < 6; j++) colp[j] = -INFINITY;
  for (int i = 0; i < 6; i++)
    for (int rg = 0; rg < 4; rg++) rowp[i][rg] = -INFINITY;
  for (int i = 0; i < 6; i++) {
    for (int j = 0; j < 6; j++) {
      int t = wt * 96 + j * 16 + lr;
      for (int rg = 0; rg < 4; rg++) {
        int s = ws * 96 + i * 16 + lq * 4 + rg;
        float v = acc[i][j][rg] * gaten[s * 192 + t];
        colp[j] = fmaxf(colp[j], v);
        rowp[i][rg] = fmaxf(rowp[i][rg], v);
      }
    }
  }
  for (int j = 0; j < 6; j++)
    colL[(ws * 4 + lq) * 192 + wt * 96 + j * 16 + lr] = colp[j];
  for (int i = 0; i < 6; i++)
    for (int rg = 0; rg < 4; rg++) {
      float v = rowp[i][rg];
      v = fmaxf(v, __shfl_xor(v, 1));
      v = fmaxf(v, __shfl_xor(v, 2));
      v = fmaxf(v, __shfl_xor(v, 4));
      v = fmaxf(v, __shfl_xor(v, 8));
      if (lr == 0) rowL[wt * 192 + ws * 96 + i * 16 + lq * 4 + rg] = v;
    }
  __syncthreads();

  const float g1 = bn1g[n] * BN_SCALE;
  const float bb1 = bn1b[n];
  u16* outp = pooled + ((size_t)n * 2304 + (size_t)qIdx * 48 + kIdx) * 384;
  for (int id = tid; id < 384; id += 256) {
    if (id < 192) {
      float m = colL[id];
      for (int w = 1; w < 8; w++) m = fmaxf(m, colL[w * 192 + id]);
      outp[id] = f2bf(m * g1 + bb1);
    } else {
      int s = id - 192;
      float m = fmaxf(rowL[s], rowL[192 + s]);
      outp[id] = f2bf(m * g1 + bb1);
    }
  }
}

// ---------------- K4: fused fc2(alpha-folded) + relu + fc3 partials ----------------
// rows = pooled[n] [4608][192] (bf16); w2B bf16 pre-scaled by bn2 alpha.
__global__ __launch_bounds__(256, 1) void k_mlp(
    const u16* __restrict__ pooled, const u16* __restrict__ w2B,
    const float* __restrict__ beta2, const float* __restrict__ w3,
    float* __restrict__ r) {
  __shared__ u16 Xt[128 * 64];
  __shared__ u16 Wt[128 * 64];
  const int tid = threadIdx.x, lane = tid & 63, wave = tid >> 6;
  const int n = blockIdx.z, row0 = blockIdx.y * 128, f0 = blockIdx.x * 512;
  const u16* X = pooled + ((size_t)n * 4608 + row0) * 192;  // ld 192 bf16
  const u16* W = w2B + (size_t)n * 2048 * 192;              // ld 192 bf16
  const int wr = wave >> 1, wc = wave & 1;
  const int lr = lane & 15, lq = lane >> 4;
  const int sw = lr & 7;
  const int cc0 = (lq ^ sw) << 3, cc1 = ((lq + 4) ^ sw) << 3;
  float rp[4][4];
  for (int i = 0; i < 4; i++)
    for (int rg = 0; rg < 4; rg++) rp[i][rg] = 0.f;

  for (int fs = 0; fs < 4; ++fs) {
    const int fb = f0 + fs * 128;
    floatx4 acc[4][4];
    for (int i = 0; i < 4; i++)
      for (int j = 0; j < 4; j++) acc[i][j] = (floatx4){0.f, 0.f, 0.f, 0.f};
    for (int kk = 0; kk < 3; ++kk) {
      const int k0 = kk * 64;
      __syncthreads();
      for (int it = 0; it < 4; ++it) {
        int chb = it * 256 + wave * 64;   // wave-uniform chunk base
        int ch = chb + lane;
        int row = ch >> 3, cc = ch & 7;
        int scc = ((cc ^ (row & 7)) << 3);  // swizzled source col-chunk
        gload_lds16(X + (size_t)row * 192 + k0 + scc, &Xt[chb * 8]);
        gload_lds16(W + (size_t)(fb + row) * 192 + k0 + scc, &Wt[chb * 8]);
      }
      __syncthreads();
#pragma unroll
      for (int k2 = 0; k2 < 2; ++k2) {
        const int cco = k2 ? cc1 : cc0;
        bfrag8 a[4], b[4];
        for (int i = 0; i < 4; i++)
          a[i] = *(const bfrag8*)&Xt[(wr * 64 + i * 16 + lr) * 64 + cco];
        for (int j = 0; j < 4; j++)
          b[j] = *(const bfrag8*)&Wt[(wc * 64 + j * 16 + lr) * 64 + cco];
        for (int i = 0; i < 4; i++)
          for (int j = 0; j < 4; j++) acc[i][j] = mfma16(a[i], b[j], acc[i][j]);
      }
    }
    for (int j = 0; j < 4; j++) {
      int f = fb + wc * 64 + j * 16 + lr;
      float beta = beta2[n * 2048 + f];
      float w3f = w3[n * 2048 + f];
      for (int i = 0; i < 4; i++)
        for (int rg = 0; rg < 4; rg++) {
          float y = acc[i][j][rg] + beta;
          y = fmaxf(y, 0.f);
          rp[i][rg] += y * w3f;
        }
    }
  }
  for (int i = 0; i < 4; i++)
    for (int rg = 0; rg < 4; rg++) {
      float v = rp[i][rg];
      v += __shfl_xor(v, 1);
      v += __shfl_xor(v, 2);
      v += __shfl_xor(v, 4);
      v += __shfl_xor(v, 8);
      if (lr == 0) {
        int row = row0 + wr * 64 + i * 16 + lq * 4 + rg;
        atomicAdd(&r[n * 4608 + row], v);
      }
    }
}

// ---------------- K5: pair sum + bn3 + layer sum + final norm ----------------
__global__ void k_final(const float* __restrict__ r, const float* __restrict__ b3,
                        const float* __restrict__ g3, const float* __restrict__ bb3,
                        const float* __restrict__ ng, const float* __restrict__ nb,
                        float* __restrict__ out) {
  int p = blockIdx.x * 256 + threadIdx.x;
  if (p >= 2304) return;
  float acc = 0.f;
  for (int n = 0; n < 3; ++n) {
    float z = r[n * 4608 + 2 * p] + r[n * 4608 + 2 * p + 1] + 2.f * b3[n];
    acc += z * (g3[n] * BN_SCALE) + bb3[n];
  }
  out[p] = acc * (ng[0] * BN_SCALE) + nb[0];
}

extern "C" void kernel_launch(void* const* d_in, const int* in_sizes, int n_in,
                              void* d_out, int out_size, void* d_ws, size_t ws_size,
                              hipStream_t stream) {
  const float* memory = (const float*)d_in[0];
  const float* features = (const float*)d_in[1];
  const float* fc1_w = (const float*)d_in[2];
  const float* fc1_b = (const float*)d_in[3];
  const float* se = (const float*)d_in[4];
  const float* bn1_g = (const float*)d_in[5];
  const float* bn1_b = (const float*)d_in[6];
  const float* fc2_w = (const float*)d_in[7];
  const float* fc2_b = (const float*)d_in[8];
  const float* bn2_g = (const float*)d_in[9];
  const float* bn2_b = (const float*)d_in[10];
  const float* fc3_w = (const float*)d_in[11];
  const float* fc3_b = (const float*)d_in[12];
  const float* bn3_g = (const float*)d_in[13];
  const float* bn3_b = (const float*)d_in[14];
  const float* norm_g = (const float*)d_in[15];
  const float* norm_b = (const float*)d_in[16];

  char* ws = (char*)d_ws;
  float* gate = (float*)ws;                       // 442,368 B
  u16* w2B = (u16*)(ws + 442368);                 // 2,359,296 B
  float* beta2 = (float*)(ws + 2801664);          // 24,576 B
  u16* qB = (u16*)(ws + 2826240);                 // 28,311,552 B
  u16* kB = (u16*)(ws + 31137792);                // 28,311,552 B
  u16* pooled = (u16*)(ws + 59449344);            // 5,308,416 B
  float* r = (float*)(ws + 64757760);             // 55,296 B

  hipMemsetAsync(r, 0, 3 * 4608 * sizeof(float), stream);
  k_prep<<<dim3(5064), 256, 0, stream>>>(se, gate, fc2_w, bn2_g, fc2_b, bn2_b,
                                         w2B, beta2);
  k_fc1<<<dim3(4, 72, 6), 256, 0, stream>>>(memory, features, fc1_w, fc1_b, qB, kB);
  k_score<<<dim3(2304, 3), 256, 0, stream>>>(qB, kB, gate, bn1_g, bn1_b, pooled);
  k_mlp<<<dim3(4, 36, 3), 256, 0, stream>>>(pooled, w2B, beta2, fc3_w, r);
  k_final<<<dim3(9), 256, 0, stream>>>(r, fc3_b, bn3_g, bn3_b, norm_g, norm_b,
                                       (float*)d_out);
}